// Round 2
// baseline (1818.142 us; speedup 1.0000x reference)
//
#include <hip/hip_runtime.h>
#include <hip/hip_bf16.h>

#define Q_TOT 1024
#define T_TOT 256
#define NPTS  100
#define KD    300
#define EPSV  1e-6f

// ---------------------------------------------------------------------------
// 50 shifted dot-products against one query's 300-float pred row.
// S[c][x] = tgt_ext[x+c] (byte-rotated copies so every read is an aligned b128).
// A[v=ABASE+u, k] = tgt_ext[300 - 3v + k].  ABASE is compile-time so the LDS
// offsets fold into ds_read immediates (single shared address register = kc*16).
// ---------------------------------------------------------------------------
template<int ABASE>
__device__ __forceinline__ void dot_tile(const float (&S)[4][608],
                                         const float4* __restrict__ pp,
                                         float (&acc)[50], float& p2)
{
    float4 p4 = pp[0];
    for (int kc = 0; kc < 75; ++kc) {
        float4 p4n = pp[(kc+1 < 75) ? (kc+1) : 74];   // prefetch next chunk
        p2 = fmaf(p4.x,p4.x, fmaf(p4.y,p4.y, fmaf(p4.z,p4.z, fmaf(p4.w,p4.w, p2))));
        #pragma unroll
        for (int u = 0; u < 50; ++u) {
            const int a   = ABASE + u;          // shift amount (compile-time)
            const int off = 300 - 3*a;          // base into tgt_ext
            const int c   = off & 3;            // which rotated copy
            const int y   = (off - c) + kc*4;   // 16B-aligned float index
            const float4 a4 = *reinterpret_cast<const float4*>(&S[c][y]);
            acc[u] = fmaf(a4.x,p4.x, fmaf(a4.y,p4.y, fmaf(a4.z,p4.z, fmaf(a4.w,p4.w, acc[u]))));
        }
        p4 = p4n;
    }
}

// ---------------------------------------------------------------------------
// Main: one block = one target t x 64 queries.  256 threads = 4 variant-groups
// (waves) x 64 queries.  Each thread: 50 variants x 300-MAC dot products.
// Cost-class softmax terms are computed inline in the epilogue (no workspace).
// ---------------------------------------------------------------------------
__global__ __launch_bounds__(256) void matcher_main(
    const float* __restrict__ preds,   // [1024][300]
    const float* __restrict__ plog,    // [1024][2]  pred_curve_logits
    const float* __restrict__ ptyp,    // [1024][4]  pred_curve_type
    const float* __restrict__ clog,    // [1024][2]  closed_curve_logits
    const float* __restrict__ tgt,     // [256][300]
    const int*   __restrict__ labels,  // [256]
    const int*   __restrict__ iscl,    // [256]
    const float* __restrict__ clw,     // [256]
    float* __restrict__ out)           // [2][1024][256] flat fp32
{
    __shared__ __align__(16) float sF[4][608];   // fwd tgt_ext, 4 rotated copies
    __shared__ __align__(16) float sR[4][608];   // reversed tgt_ext, 4 copies
    __shared__ float red_min[4][64];
    __shared__ int   red_idx[4][64];
    __shared__ float red_open[2][64];

    const int t   = blockIdx.x;
    const int qt  = blockIdx.y;
    const int tid = threadIdx.x;
    const int ql  = tid & 63;
    const int vg  = tid >> 6;          // 0..3, wave-uniform
    const int q   = qt*64 + ql;

    // Stage tgt_ext (600 = doubled 300) fwd + reversed, 4 byte-rotated copies.
    const float* tg = tgt + t*KD;
    for (int i = tid; i < 600; i += 256) {
        int m = (i >= 300) ? (i-300) : i;
        float vF = tg[m];
        int jj = m / 3;
        int c3 = m - jj*3;
        float vR = tg[(NPTS-1-jj)*3 + c3];
        #pragma unroll
        for (int c = 0; c < 4; ++c) {
            int x = i - c;
            if (x >= 0) { sF[c][x] = vF; sR[c][x] = vR; }
        }
    }
    __syncthreads();

    // v2 = sum(tgt^2) -- per-thread redundant compute (broadcast reads)
    float v2 = 0.f;
    {
        const float4* tf4 = reinterpret_cast<const float4*>(&sF[0][300]); // = tg[0..299]
        #pragma unroll
        for (int i2 = 0; i2 < 75; ++i2) {
            float4 w = tf4[i2];
            v2 = fmaf(w.x,w.x, fmaf(w.y,w.y, fmaf(w.z,w.z, fmaf(w.w,w.w, v2))));
        }
    }

    float acc[50];
    #pragma unroll
    for (int u = 0; u < 50; ++u) acc[u] = 0.f;
    float p2 = 0.f;
    const float4* pp = reinterpret_cast<const float4*>(preds + q*KD);
    switch (vg) {                       // wave-uniform branch
        case 0:  dot_tile<0 >(sF, pp, acc, p2); break;   // v =   0..49  (fwd)
        case 1:  dot_tile<50>(sF, pp, acc, p2); break;   // v =  50..99  (fwd)
        case 2:  dot_tile<0 >(sR, pp, acc, p2); break;   // v = 100..149 (bwd a=0..49)
        default: dot_tile<50>(sR, pp, acc, p2); break;   // v = 150..199 (bwd a=50..99)
    }

    // Local min/argmin in ascending v (replicates jnp.argmin first-occurrence).
    const float s2 = v2 + p2;
    float dmin = 3.4028235e38f; int imin = 0; float d2first = 0.f;
    #pragma unroll
    for (int u = 0; u < 50; ++u) {
        float d2 = fmaxf(fmaf(-2.f, acc[u], s2), 0.f) * 0.01f;
        if (u == 0) d2first = d2;
        if (d2 < dmin) { dmin = d2; imin = vg*50 + u; }
    }
    red_min[vg][ql] = dmin;
    red_idx[vg][ql] = imin;
    if (vg == 0) red_open[0][ql] = d2first;   // d2[v=0]
    if (vg == 2) red_open[1][ql] = d2first;   // d2[v=100]
    __syncthreads();

    if (tid < 64) {
        float mbest = red_min[0][tid]; int ibest = red_idx[0][tid];
        #pragma unroll
        for (int g = 1; g < 4; ++g) {         // ascending v-groups, strict <
            float mg = red_min[g][tid];
            if (mg < mbest) { mbest = mg; ibest = red_idx[g][tid]; }
        }
        int mapped = (ibest <= NPTS-1) ? ibest : (2*NPTS-1 - ibest);
        float od   = fminf(red_open[0][tid], red_open[1][tid]);
        int   isc  = iscl[t];                 // 0 or 1
        float geom = isc ? mbest : od;
        int   ido  = isc ? mapped : 0;
        geom *= clw[t];

        // Inline cost-class terms for query qg, target t.
        const int qg = qt*64 + tid;
        float t0 = ptyp[qg*4+0], t1 = ptyp[qg*4+1];
        float t2 = ptyp[qg*4+2], t3 = ptyp[qg*4+3];
        float mx = fmaxf(fmaxf(t0,t1), fmaxf(t2,t3));
        float e0 = expf(t0-mx), e1 = expf(t1-mx), e2 = expf(t2-mx), e3 = expf(t3-mx);
        float rs = 1.0f/(e0+e1+e2+e3);
        int lab  = labels[t];
        float el = (lab == 0) ? e0 : (lab == 1) ? e1 : (lab == 2) ? e2 : e3;
        float cost = -logf(el*rs + EPSV);
        float v0 = plog[qg*2+0], v1 = plog[qg*2+1];
        cost += -logf(1.0f/(1.0f + expf(v1-v0)) + EPSV);
        float c0 = clog[qg*2+0], c1 = clog[qg*2+1];
        float pc = isc ? (1.0f/(1.0f + expf(c0-c1))) : (1.0f/(1.0f + expf(c1-c0)));
        cost += -logf(pc + EPSV);

        float C = geom + cost;
        out[qg*T_TOT + t]               = C;
        out[Q_TOT*T_TOT + qg*T_TOT + t] = (float)ido;
    }
}

extern "C" void kernel_launch(void* const* d_in, const int* in_sizes, int n_in,
                              void* d_out, int out_size, void* d_ws, size_t ws_size,
                              hipStream_t stream)
{
    const float* preds  = (const float*)d_in[0];  // pred_curve_points (1,1024,100,3)
    const float* plog   = (const float*)d_in[1];  // pred_curve_logits (1,1024,2)
    const float* ptyp   = (const float*)d_in[2];  // pred_curve_type   (1,1024,4)
    const float* clog   = (const float*)d_in[3];  // closed_curve_logits (1,1024,2)
    const float* tgt    = (const float*)d_in[4];  // tgt_curve_points  (256,100,3)
    const int*   labels = (const int*)d_in[5];    // tgt_labels (256)
    const int*   iscl   = (const int*)d_in[6];    // tgt_is_closed (256)
    const float* clw    = (const float*)d_in[7];  // curve_length_weighting (256)
    float* out = (float*)d_out;

    matcher_main<<<dim3(T_TOT, Q_TOT/64), dim3(256), 0, stream>>>(
        preds, plog, ptyp, clog, tgt, labels, iscl, clw, out);
}

// Round 3
// 1060.597 us; speedup vs baseline: 1.7143x; 1.7143x over previous
//
#include <hip/hip_runtime.h>
#include <hip/hip_bf16.h>

#define Q_TOT 1024
#define T_TOT 256
#define NPTS  100
#define KD    300
#define EPSV  1e-6f

// ---------------------------------------------------------------------------
// 25 shifted dot-products for TWO queries against one target's tgt_ext.
// S[c][x] = tgt_ext[x+c] (byte-rotated copies so every read is an aligned b128
// with compile-time offset).  Each LDS read feeds 8 FMAs (2 queries x float4).
// A[v, k] = tgt_ext[300 - 3a + k], a = ABASE + u.
// ---------------------------------------------------------------------------
template<int ABASE>
__device__ __forceinline__ void dot_tile2(const float (&S)[4][608],
                                          const float4* __restrict__ ppa,
                                          const float4* __restrict__ ppb,
                                          float (&accA)[25], float (&accB)[25],
                                          float& p2a, float& p2b)
{
    float4 pa = ppa[0], pb = ppb[0];
    for (int kc = 0; kc < 75; ++kc) {
        float4 pan = ppa[(kc+1 < 75) ? (kc+1) : 74];   // prefetch next chunks
        float4 pbn = ppb[(kc+1 < 75) ? (kc+1) : 74];
        p2a = fmaf(pa.x,pa.x, fmaf(pa.y,pa.y, fmaf(pa.z,pa.z, fmaf(pa.w,pa.w, p2a))));
        p2b = fmaf(pb.x,pb.x, fmaf(pb.y,pb.y, fmaf(pb.z,pb.z, fmaf(pb.w,pb.w, p2b))));
        #pragma unroll
        for (int u = 0; u < 25; ++u) {
            const int a   = ABASE + u;          // shift amount (compile-time)
            const int off = 300 - 3*a;          // base into tgt_ext
            const int c   = off & 3;            // which rotated copy
            const int y   = (off - c) + kc*4;   // 16B-aligned float index
            const float4 a4 = *reinterpret_cast<const float4*>(&S[c][y]);
            accA[u] = fmaf(a4.x,pa.x, fmaf(a4.y,pa.y, fmaf(a4.z,pa.z, fmaf(a4.w,pa.w, accA[u]))));
            accB[u] = fmaf(a4.x,pb.x, fmaf(a4.y,pb.y, fmaf(a4.z,pb.z, fmaf(a4.w,pb.w, accB[u]))));
        }
        pa = pan; pb = pbn;
    }
}

// ---------------------------------------------------------------------------
// One block = one target t x 128 queries.  512 threads = 8 variant-groups
// (waves) x 64 lanes; each thread: 25 variants x 2 queries x 300-MAC dots.
// v = 25*vg + u  (ascending across groups -> first-occurrence argmin holds).
// ---------------------------------------------------------------------------
__global__ __launch_bounds__(512, 4) void matcher_main(
    const float* __restrict__ preds,   // [1024][300]
    const float* __restrict__ plog,    // [1024][2]
    const float* __restrict__ ptyp,    // [1024][4]
    const float* __restrict__ clog,    // [1024][2]
    const float* __restrict__ tgt,     // [256][300]
    const int*   __restrict__ labels,  // [256]
    const int*   __restrict__ iscl,    // [256]
    const float* __restrict__ clw,     // [256]
    float* __restrict__ out)           // [2][1024][256] flat fp32
{
    __shared__ __align__(16) float sF[4][608];   // fwd tgt_ext, 4 rotated copies
    __shared__ __align__(16) float sR[4][608];   // reversed tgt_ext, 4 copies
    __shared__ float red_min[8][128];
    __shared__ int   red_idx[8][128];
    __shared__ float red_open[2][128];

    const int t    = blockIdx.x;
    const int qt   = blockIdx.y;
    const int tid  = threadIdx.x;
    const int lane = tid & 63;
    const int vg   = tid >> 6;          // 0..7, wave-uniform
    const int qa   = qt*128 + lane;     // query A
    const int qb   = qa + 64;           // query B

    // Stage tgt_ext (doubled 300) fwd + reversed, 4 byte-rotated copies.
    const float* tg = tgt + t*KD;
    for (int i = tid; i < 600; i += 512) {
        int m = (i >= 300) ? (i-300) : i;
        float vF = tg[m];
        int jj = m / 3;
        int c3 = m - jj*3;
        float vR = tg[(NPTS-1-jj)*3 + c3];
        #pragma unroll
        for (int c = 0; c < 4; ++c) {
            int x = i - c;
            if (x >= 0) { sF[c][x] = vF; sR[c][x] = vR; }
        }
    }
    __syncthreads();

    // v2 = sum(tgt^2) -- broadcast LDS reads, ~3 kc-iterations of cost
    float v2 = 0.f;
    {
        const float4* tf4 = reinterpret_cast<const float4*>(&sF[0][300]); // = tg[0..299]
        #pragma unroll
        for (int i2 = 0; i2 < 75; ++i2) {
            float4 w = tf4[i2];
            v2 = fmaf(w.x,w.x, fmaf(w.y,w.y, fmaf(w.z,w.z, fmaf(w.w,w.w, v2))));
        }
    }

    float accA[25], accB[25];
    #pragma unroll
    for (int u = 0; u < 25; ++u) { accA[u] = 0.f; accB[u] = 0.f; }
    float p2a = 0.f, p2b = 0.f;
    const float4* ppa = reinterpret_cast<const float4*>(preds + qa*KD);
    const float4* ppb = reinterpret_cast<const float4*>(preds + qb*KD);
    switch (vg) {                       // wave-uniform branch
        case 0:  dot_tile2<0 >(sF, ppa, ppb, accA, accB, p2a, p2b); break; // v=  0..24
        case 1:  dot_tile2<25>(sF, ppa, ppb, accA, accB, p2a, p2b); break; // v= 25..49
        case 2:  dot_tile2<50>(sF, ppa, ppb, accA, accB, p2a, p2b); break; // v= 50..74
        case 3:  dot_tile2<75>(sF, ppa, ppb, accA, accB, p2a, p2b); break; // v= 75..99
        case 4:  dot_tile2<0 >(sR, ppa, ppb, accA, accB, p2a, p2b); break; // v=100..124
        case 5:  dot_tile2<25>(sR, ppa, ppb, accA, accB, p2a, p2b); break; // v=125..149
        case 6:  dot_tile2<50>(sR, ppa, ppb, accA, accB, p2a, p2b); break; // v=150..174
        default: dot_tile2<75>(sR, ppa, ppb, accA, accB, p2a, p2b); break; // v=175..199
    }

    // Local min/argmin in ascending v (first-occurrence semantics via strict <).
    const float s2a = v2 + p2a, s2b = v2 + p2b;
    float dminA = 3.4028235e38f, dminB = 3.4028235e38f;
    int   iminA = 0, iminB = 0;
    float dfA = 0.f, dfB = 0.f;
    #pragma unroll
    for (int u = 0; u < 25; ++u) {
        float dA = fmaxf(fmaf(-2.f, accA[u], s2a), 0.f) * 0.01f;
        float dB = fmaxf(fmaf(-2.f, accB[u], s2b), 0.f) * 0.01f;
        if (u == 0) { dfA = dA; dfB = dB; }
        if (dA < dminA) { dminA = dA; iminA = 25*vg + u; }
        if (dB < dminB) { dminB = dB; iminB = 25*vg + u; }
    }
    red_min[vg][lane]    = dminA;  red_min[vg][lane+64] = dminB;
    red_idx[vg][lane]    = iminA;  red_idx[vg][lane+64] = iminB;
    if (vg == 0) { red_open[0][lane] = dfA; red_open[0][lane+64] = dfB; } // d2[v=0]
    if (vg == 4) { red_open[1][lane] = dfA; red_open[1][lane+64] = dfB; } // d2[v=100]
    __syncthreads();

    if (tid < 128) {
        float mbest = red_min[0][tid]; int ibest = red_idx[0][tid];
        #pragma unroll
        for (int g = 1; g < 8; ++g) {         // ascending v-groups, strict <
            float mg = red_min[g][tid];
            if (mg < mbest) { mbest = mg; ibest = red_idx[g][tid]; }
        }
        int mapped = (ibest <= NPTS-1) ? ibest : (2*NPTS-1 - ibest);
        float od   = fminf(red_open[0][tid], red_open[1][tid]);
        int   isc  = iscl[t];                 // 0 or 1
        float geom = isc ? mbest : od;
        int   ido  = isc ? mapped : 0;
        geom *= clw[t];

        // Inline cost-class terms for query qg, target t.
        const int qg = qt*128 + tid;
        float t0 = ptyp[qg*4+0], t1 = ptyp[qg*4+1];
        float t2 = ptyp[qg*4+2], t3 = ptyp[qg*4+3];
        float mx = fmaxf(fmaxf(t0,t1), fmaxf(t2,t3));
        float e0 = expf(t0-mx), e1 = expf(t1-mx), e2 = expf(t2-mx), e3 = expf(t3-mx);
        float rs = 1.0f/(e0+e1+e2+e3);
        int lab  = labels[t];
        float el = (lab == 0) ? e0 : (lab == 1) ? e1 : (lab == 2) ? e2 : e3;
        float cost = -logf(el*rs + EPSV);
        float v0 = plog[qg*2+0], v1 = plog[qg*2+1];
        cost += -logf(1.0f/(1.0f + expf(v1-v0)) + EPSV);
        float c0 = clog[qg*2+0], c1 = clog[qg*2+1];
        float pc = isc ? (1.0f/(1.0f + expf(c0-c1))) : (1.0f/(1.0f + expf(c1-c0)));
        cost += -logf(pc + EPSV);

        float C = geom + cost;
        out[qg*T_TOT + t]               = C;
        out[Q_TOT*T_TOT + qg*T_TOT + t] = (float)ido;
    }
}

extern "C" void kernel_launch(void* const* d_in, const int* in_sizes, int n_in,
                              void* d_out, int out_size, void* d_ws, size_t ws_size,
                              hipStream_t stream)
{
    const float* preds  = (const float*)d_in[0];  // pred_curve_points (1,1024,100,3)
    const float* plog   = (const float*)d_in[1];  // pred_curve_logits (1,1024,2)
    const float* ptyp   = (const float*)d_in[2];  // pred_curve_type   (1,1024,4)
    const float* clog   = (const float*)d_in[3];  // closed_curve_logits (1,1024,2)
    const float* tgt    = (const float*)d_in[4];  // tgt_curve_points  (256,100,3)
    const int*   labels = (const int*)d_in[5];    // tgt_labels (256)
    const int*   iscl   = (const int*)d_in[6];    // tgt_is_closed (256)
    const float* clw    = (const float*)d_in[7];  // curve_length_weighting (256)
    float* out = (float*)d_out;

    matcher_main<<<dim3(T_TOT, Q_TOT/128), dim3(512), 0, stream>>>(
        preds, plog, ptyp, clog, tgt, labels, iscl, clw, out);
}

// Round 4
// 938.371 us; speedup vs baseline: 1.9376x; 1.1303x over previous
//
#include <hip/hip_runtime.h>
#include <hip/hip_bf16.h>

#define Q_TOT 1024
#define T_TOT 256
#define NPTS  100
#define KD    300
#define EPSV  1e-6f

// ---------------------------------------------------------------------------
// 25 shifted dot-products for TWO queries against one target's tgt_ext.
// S[c][x] = tgt_ext[x+c] (byte-rotated copies so every read is an aligned b128
// with compile-time offset).  Each LDS read feeds 8 FMAs (2 queries x float4).
// A[v, k] = tgt_ext[300 - 3a + k], a = ABASE + u.
// ---------------------------------------------------------------------------
template<int ABASE>
__device__ __forceinline__ void dot_tile2(const float (&S)[4][608],
                                          const float4* __restrict__ ppa,
                                          const float4* __restrict__ ppb,
                                          float (&accA)[25], float (&accB)[25],
                                          float& p2a, float& p2b)
{
    for (int kc = 0; kc < 75; ++kc) {
        float4 pa = ppa[kc];
        float4 pb = ppb[kc];
        p2a = fmaf(pa.x,pa.x, fmaf(pa.y,pa.y, fmaf(pa.z,pa.z, fmaf(pa.w,pa.w, p2a))));
        p2b = fmaf(pb.x,pb.x, fmaf(pb.y,pb.y, fmaf(pb.z,pb.z, fmaf(pb.w,pb.w, p2b))));
        #pragma unroll
        for (int u = 0; u < 25; ++u) {
            const int a   = ABASE + u;          // shift amount (compile-time)
            const int off = 300 - 3*a;          // base into tgt_ext
            const int c   = off & 3;            // which rotated copy
            const int y   = (off - c) + kc*4;   // 16B-aligned float index
            const float4 a4 = *reinterpret_cast<const float4*>(&S[c][y]);
            accA[u] = fmaf(a4.x,pa.x, fmaf(a4.y,pa.y, fmaf(a4.z,pa.z, fmaf(a4.w,pa.w, accA[u]))));
            accB[u] = fmaf(a4.x,pb.x, fmaf(a4.y,pb.y, fmaf(a4.z,pb.z, fmaf(a4.w,pb.w, accB[u]))));
        }
    }
}

// ---------------------------------------------------------------------------
// One block = one target t x 128 queries.  512 threads = 8 variant-groups
// (waves) x 64 lanes; each thread: 25 variants x 2 queries x 300-MAC dots.
// v = 25*vg + u  (ascending across groups -> first-occurrence argmin holds).
// launch_bounds min-waves=2: allow up to 256 VGPRs -- R3's (512,4) clamped to
// 64 VGPRs and spilled ~1.6 GB/launch of scratch to HBM.
// ---------------------------------------------------------------------------
__global__ __launch_bounds__(512, 2) void matcher_main(
    const float* __restrict__ preds,   // [1024][300]
    const float* __restrict__ plog,    // [1024][2]
    const float* __restrict__ ptyp,    // [1024][4]
    const float* __restrict__ clog,    // [1024][2]
    const float* __restrict__ tgt,     // [256][300]
    const int*   __restrict__ labels,  // [256]
    const int*   __restrict__ iscl,    // [256]
    const float* __restrict__ clw,     // [256]
    float* __restrict__ out)           // [2][1024][256] flat fp32
{
    __shared__ __align__(16) float sF[4][608];   // fwd tgt_ext, 4 rotated copies
    __shared__ __align__(16) float sR[4][608];   // reversed tgt_ext, 4 copies
    __shared__ float red_min[8][128];
    __shared__ int   red_idx[8][128];
    __shared__ float red_open[2][128];

    const int t    = blockIdx.x;
    const int qt   = blockIdx.y;
    const int tid  = threadIdx.x;
    const int lane = tid & 63;
    const int vg   = tid >> 6;          // 0..7, wave-uniform
    const int qa   = qt*128 + lane;     // query A
    const int qb   = qa + 64;           // query B

    // Stage tgt_ext (doubled 300) fwd + reversed, 4 byte-rotated copies.
    const float* tg = tgt + t*KD;
    for (int i = tid; i < 600; i += 512) {
        int m = (i >= 300) ? (i-300) : i;
        float vF = tg[m];
        int jj = m / 3;
        int c3 = m - jj*3;
        float vR = tg[(NPTS-1-jj)*3 + c3];
        #pragma unroll
        for (int c = 0; c < 4; ++c) {
            int x = i - c;
            if (x >= 0) { sF[c][x] = vF; sR[c][x] = vR; }
        }
    }
    __syncthreads();

    // v2 = sum(tgt^2) -- broadcast LDS reads
    float v2 = 0.f;
    {
        const float4* tf4 = reinterpret_cast<const float4*>(&sF[0][300]); // = tg[0..299]
        #pragma unroll
        for (int i2 = 0; i2 < 75; ++i2) {
            float4 w = tf4[i2];
            v2 = fmaf(w.x,w.x, fmaf(w.y,w.y, fmaf(w.z,w.z, fmaf(w.w,w.w, v2))));
        }
    }

    float accA[25], accB[25];
    #pragma unroll
    for (int u = 0; u < 25; ++u) { accA[u] = 0.f; accB[u] = 0.f; }
    float p2a = 0.f, p2b = 0.f;
    const float4* ppa = reinterpret_cast<const float4*>(preds + qa*KD);
    const float4* ppb = reinterpret_cast<const float4*>(preds + qb*KD);
    switch (vg) {                       // wave-uniform branch
        case 0:  dot_tile2<0 >(sF, ppa, ppb, accA, accB, p2a, p2b); break; // v=  0..24
        case 1:  dot_tile2<25>(sF, ppa, ppb, accA, accB, p2a, p2b); break; // v= 25..49
        case 2:  dot_tile2<50>(sF, ppa, ppb, accA, accB, p2a, p2b); break; // v= 50..74
        case 3:  dot_tile2<75>(sF, ppa, ppb, accA, accB, p2a, p2b); break; // v= 75..99
        case 4:  dot_tile2<0 >(sR, ppa, ppb, accA, accB, p2a, p2b); break; // v=100..124
        case 5:  dot_tile2<25>(sR, ppa, ppb, accA, accB, p2a, p2b); break; // v=125..149
        case 6:  dot_tile2<50>(sR, ppa, ppb, accA, accB, p2a, p2b); break; // v=150..174
        default: dot_tile2<75>(sR, ppa, ppb, accA, accB, p2a, p2b); break; // v=175..199
    }

    // Local min/argmin in ascending v (first-occurrence semantics via strict <).
    const float s2a = v2 + p2a, s2b = v2 + p2b;
    float dminA = 3.4028235e38f, dminB = 3.4028235e38f;
    int   iminA = 0, iminB = 0;
    float dfA = 0.f, dfB = 0.f;
    #pragma unroll
    for (int u = 0; u < 25; ++u) {
        float dA = fmaxf(fmaf(-2.f, accA[u], s2a), 0.f) * 0.01f;
        float dB = fmaxf(fmaf(-2.f, accB[u], s2b), 0.f) * 0.01f;
        if (u == 0) { dfA = dA; dfB = dB; }
        if (dA < dminA) { dminA = dA; iminA = 25*vg + u; }
        if (dB < dminB) { dminB = dB; iminB = 25*vg + u; }
    }
    red_min[vg][lane]    = dminA;  red_min[vg][lane+64] = dminB;
    red_idx[vg][lane]    = iminA;  red_idx[vg][lane+64] = iminB;
    if (vg == 0) { red_open[0][lane] = dfA; red_open[0][lane+64] = dfB; } // d2[v=0]
    if (vg == 4) { red_open[1][lane] = dfA; red_open[1][lane+64] = dfB; } // d2[v=100]
    __syncthreads();

    if (tid < 128) {
        float mbest = red_min[0][tid]; int ibest = red_idx[0][tid];
        #pragma unroll
        for (int g = 1; g < 8; ++g) {         // ascending v-groups, strict <
            float mg = red_min[g][tid];
            if (mg < mbest) { mbest = mg; ibest = red_idx[g][tid]; }
        }
        int mapped = (ibest <= NPTS-1) ? ibest : (2*NPTS-1 - ibest);
        float od   = fminf(red_open[0][tid], red_open[1][tid]);
        int   isc  = iscl[t];                 // 0 or 1
        float geom = isc ? mbest : od;
        int   ido  = isc ? mapped : 0;
        geom *= clw[t];

        // Inline cost-class terms for query qg, target t.
        const int qg = qt*128 + tid;
        float t0 = ptyp[qg*4+0], t1 = ptyp[qg*4+1];
        float t2 = ptyp[qg*4+2], t3 = ptyp[qg*4+3];
        float mx = fmaxf(fmaxf(t0,t1), fmaxf(t2,t3));
        float e0 = expf(t0-mx), e1 = expf(t1-mx), e2 = expf(t2-mx), e3 = expf(t3-mx);
        float rs = 1.0f/(e0+e1+e2+e3);
        int lab  = labels[t];
        float el = (lab == 0) ? e0 : (lab == 1) ? e1 : (lab == 2) ? e2 : e3;
        float cost = -logf(el*rs + EPSV);
        float v0 = plog[qg*2+0], v1 = plog[qg*2+1];
        cost += -logf(1.0f/(1.0f + expf(v1-v0)) + EPSV);
        float c0 = clog[qg*2+0], c1 = clog[qg*2+1];
        float pc = isc ? (1.0f/(1.0f + expf(c0-c1))) : (1.0f/(1.0f + expf(c1-c0)));
        cost += -logf(pc + EPSV);

        float C = geom + cost;
        out[qg*T_TOT + t]               = C;
        out[Q_TOT*T_TOT + qg*T_TOT + t] = (float)ido;
    }
}

extern "C" void kernel_launch(void* const* d_in, const int* in_sizes, int n_in,
                              void* d_out, int out_size, void* d_ws, size_t ws_size,
                              hipStream_t stream)
{
    const float* preds  = (const float*)d_in[0];  // pred_curve_points (1,1024,100,3)
    const float* plog   = (const float*)d_in[1];  // pred_curve_logits (1,1024,2)
    const float* ptyp   = (const float*)d_in[2];  // pred_curve_type   (1,1024,4)
    const float* clog   = (const float*)d_in[3];  // closed_curve_logits (1,1024,2)
    const float* tgt    = (const float*)d_in[4];  // tgt_curve_points  (256,100,3)
    const int*   labels = (const int*)d_in[5];    // tgt_labels (256)
    const int*   iscl   = (const int*)d_in[6];    // tgt_is_closed (256)
    const float* clw    = (const float*)d_in[7];  // curve_length_weighting (256)
    float* out = (float*)d_out;

    matcher_main<<<dim3(T_TOT, Q_TOT/128), dim3(512), 0, stream>>>(
        preds, plog, ptyp, clog, tgt, labels, iscl, clw, out);
}

// Round 5
// 754.133 us; speedup vs baseline: 2.4109x; 1.2443x over previous
//
#include <hip/hip_runtime.h>
#include <hip/hip_bf16.h>

#define Q_TOT 1024
#define T_TOT 256
#define NPTS  100
#define KD    300
#define EPSV  1e-6f

// ---------------------------------------------------------------------------
// One pass: NU shifted dot-products for TWO queries.  S[c][x] = tgt_ext[x+c]
// (4 byte-rotated copies -> every read is an aligned b128 with compile-time
// offset, broadcast across lanes).  A[a,k] = tgt_ext[300 - 3a + k].
// P2: also accumulate sum(pred^2) (done in pass 1 only).
// Register budget is the whole game here: NU=13 keeps peak live regs ~105
// (13 b128 temps + 26 acc + 8 p + state) < 128 -> no scratch spill.
// ---------------------------------------------------------------------------
template<int ABASE, int NU, bool P2>
__device__ __forceinline__ void dot_pass(const float (&S)[4][608],
                                         const float4* __restrict__ ppa,
                                         const float4* __restrict__ ppb,
                                         float (&accA)[NU], float (&accB)[NU],
                                         float& p2a, float& p2b)
{
    #pragma unroll
    for (int u = 0; u < NU; ++u) { accA[u] = 0.f; accB[u] = 0.f; }
    #pragma clang loop unroll(disable)
    for (int kc = 0; kc < 75; ++kc) {
        float4 pa = ppa[kc];
        float4 pb = ppb[kc];
        if (P2) {
            p2a = fmaf(pa.x,pa.x, fmaf(pa.y,pa.y, fmaf(pa.z,pa.z, fmaf(pa.w,pa.w, p2a))));
            p2b = fmaf(pb.x,pb.x, fmaf(pb.y,pb.y, fmaf(pb.z,pb.z, fmaf(pb.w,pb.w, p2b))));
        }
        #pragma unroll
        for (int u = 0; u < NU; ++u) {
            const int a   = ABASE + u;          // shift amount (compile-time)
            const int off = 300 - 3*a;          // base into tgt_ext
            const int c   = off & 3;            // which rotated copy
            const int y   = (off - c) + kc*4;   // 16B-aligned float index
            const float4 a4 = *reinterpret_cast<const float4*>(&S[c][y]);
            accA[u] = fmaf(a4.x,pa.x, fmaf(a4.y,pa.y, fmaf(a4.z,pa.z, fmaf(a4.w,pa.w, accA[u]))));
            accB[u] = fmaf(a4.x,pb.x, fmaf(a4.y,pb.y, fmaf(a4.z,pb.z, fmaf(a4.w,pb.w, accB[u]))));
        }
    }
}

template<int NU>
__device__ __forceinline__ void fold_min(const float (&acc)[NU], float s2, int vbase,
                                         float& dmin, int& imin)
{
    #pragma unroll
    for (int u = 0; u < NU; ++u) {
        float d2 = fmaxf(fmaf(-2.f, acc[u], s2), 0.f) * 0.01f;
        if (d2 < dmin) { dmin = d2; imin = vbase + u; }   // strict < = first occurrence
    }
}

// 25 variants for this wave, split 13+12 so the two passes' registers never
// coexist.  Fold ascending in v after each pass.
template<int ABASE, int VBASE>
__device__ __forceinline__ void process(const float (&S)[4][608],
                                        const float4* __restrict__ ppa,
                                        const float4* __restrict__ ppb,
                                        float v2,
                                        float& dminA, int& iminA,
                                        float& dminB, int& iminB,
                                        float& dfA, float& dfB)
{
    float p2a = 0.f, p2b = 0.f;
    {
        float aA[13], aB[13];
        dot_pass<ABASE, 13, true>(S, ppa, ppb, aA, aB, p2a, p2b);
        const float s2a = v2 + p2a, s2b = v2 + p2b;
        if (VBASE == 0 || VBASE == 100) {       // d2 at v=0 (fwd) / v=100 (bwd)
            dfA = fmaxf(fmaf(-2.f, aA[0], s2a), 0.f) * 0.01f;
            dfB = fmaxf(fmaf(-2.f, aB[0], s2b), 0.f) * 0.01f;
        }
        fold_min<13>(aA, s2a, VBASE, dminA, iminA);
        fold_min<13>(aB, s2b, VBASE, dminB, iminB);
    }
    {
        float bA[12], bB[12];
        dot_pass<ABASE+13, 12, false>(S, ppa, ppb, bA, bB, p2a, p2b);
        const float s2a = v2 + p2a, s2b = v2 + p2b;
        fold_min<12>(bA, s2a, VBASE+13, dminA, iminA);
        fold_min<12>(bB, s2b, VBASE+13, dminB, iminB);
    }
}

// ---------------------------------------------------------------------------
// One block = one target t x 128 queries.  512 threads = 8 variant-groups
// (waves) x 64 lanes; each thread: 25 variants x 2 queries x 300-MAC dots.
// ---------------------------------------------------------------------------
__global__ __launch_bounds__(512, 2) void matcher_main(
    const float* __restrict__ preds,   // [1024][300]
    const float* __restrict__ plog,    // [1024][2]
    const float* __restrict__ ptyp,    // [1024][4]
    const float* __restrict__ clog,    // [1024][2]
    const float* __restrict__ tgt,     // [256][300]
    const int*   __restrict__ labels,  // [256]
    const int*   __restrict__ iscl,    // [256]
    const float* __restrict__ clw,     // [256]
    float* __restrict__ out)           // [2][1024][256] flat fp32
{
    __shared__ __align__(16) float sF[4][608];   // fwd tgt_ext, 4 rotated copies
    __shared__ __align__(16) float sR[4][608];   // reversed tgt_ext, 4 copies
    __shared__ float red_min[8][128];
    __shared__ int   red_idx[8][128];
    __shared__ float red_open[2][128];

    const int t    = blockIdx.x;
    const int qt   = blockIdx.y;
    const int tid  = threadIdx.x;
    const int lane = tid & 63;
    const int vg   = tid >> 6;          // 0..7, wave-uniform
    const int qa   = qt*128 + lane;     // query A
    const int qb   = qa + 64;           // query B

    // Stage tgt_ext (doubled 300) fwd + reversed, 4 byte-rotated copies.
    const float* tg = tgt + t*KD;
    for (int i = tid; i < 600; i += 512) {
        int m = (i >= 300) ? (i-300) : i;
        float vF = tg[m];
        int jj = m / 3;
        int c3 = m - jj*3;
        float vR = tg[(NPTS-1-jj)*3 + c3];
        #pragma unroll
        for (int c = 0; c < 4; ++c) {
            int x = i - c;
            if (x >= 0) { sF[c][x] = vF; sR[c][x] = vR; }
        }
    }
    __syncthreads();

    // v2 = sum(tgt^2) -- broadcast LDS reads
    float v2 = 0.f;
    {
        const float4* tf4 = reinterpret_cast<const float4*>(&sF[0][300]); // = tg[0..299]
        #pragma clang loop unroll(disable)
        for (int i2 = 0; i2 < 75; ++i2) {
            float4 w = tf4[i2];
            v2 = fmaf(w.x,w.x, fmaf(w.y,w.y, fmaf(w.z,w.z, fmaf(w.w,w.w, v2))));
        }
    }

    const float4* ppa = reinterpret_cast<const float4*>(preds + qa*KD);
    const float4* ppb = reinterpret_cast<const float4*>(preds + qb*KD);
    float dminA = 3.4028235e38f, dminB = 3.4028235e38f;
    int   iminA = 0, iminB = 0;
    float dfA = 0.f, dfB = 0.f;
    switch (vg) {                       // wave-uniform branch
        case 0:  process<0 ,  0>(sF, ppa, ppb, v2, dminA,iminA,dminB,iminB, dfA,dfB); break;
        case 1:  process<25, 25>(sF, ppa, ppb, v2, dminA,iminA,dminB,iminB, dfA,dfB); break;
        case 2:  process<50, 50>(sF, ppa, ppb, v2, dminA,iminA,dminB,iminB, dfA,dfB); break;
        case 3:  process<75, 75>(sF, ppa, ppb, v2, dminA,iminA,dminB,iminB, dfA,dfB); break;
        case 4:  process<0 ,100>(sR, ppa, ppb, v2, dminA,iminA,dminB,iminB, dfA,dfB); break;
        case 5:  process<25,125>(sR, ppa, ppb, v2, dminA,iminA,dminB,iminB, dfA,dfB); break;
        case 6:  process<50,150>(sR, ppa, ppb, v2, dminA,iminA,dminB,iminB, dfA,dfB); break;
        default: process<75,175>(sR, ppa, ppb, v2, dminA,iminA,dminB,iminB, dfA,dfB); break;
    }

    red_min[vg][lane]    = dminA;  red_min[vg][lane+64] = dminB;
    red_idx[vg][lane]    = iminA;  red_idx[vg][lane+64] = iminB;
    if (vg == 0) { red_open[0][lane] = dfA; red_open[0][lane+64] = dfB; } // d2[v=0]
    if (vg == 4) { red_open[1][lane] = dfA; red_open[1][lane+64] = dfB; } // d2[v=100]
    __syncthreads();

    if (tid < 128) {
        float mbest = red_min[0][tid]; int ibest = red_idx[0][tid];
        #pragma unroll
        for (int g = 1; g < 8; ++g) {         // ascending v-groups, strict <
            float mg = red_min[g][tid];
            if (mg < mbest) { mbest = mg; ibest = red_idx[g][tid]; }
        }
        int mapped = (ibest <= NPTS-1) ? ibest : (2*NPTS-1 - ibest);
        float od   = fminf(red_open[0][tid], red_open[1][tid]);
        int   isc  = iscl[t];                 // 0 or 1
        float geom = isc ? mbest : od;
        int   ido  = isc ? mapped : 0;
        geom *= clw[t];

        // Inline cost-class terms for query qg, target t.
        const int qg = qt*128 + tid;
        float t0 = ptyp[qg*4+0], t1 = ptyp[qg*4+1];
        float t2 = ptyp[qg*4+2], t3 = ptyp[qg*4+3];
        float mx = fmaxf(fmaxf(t0,t1), fmaxf(t2,t3));
        float e0 = expf(t0-mx), e1 = expf(t1-mx), e2 = expf(t2-mx), e3 = expf(t3-mx);
        float rs = 1.0f/(e0+e1+e2+e3);
        int lab  = labels[t];
        float el = (lab == 0) ? e0 : (lab == 1) ? e1 : (lab == 2) ? e2 : e3;
        float cost = -logf(el*rs + EPSV);
        float v0 = plog[qg*2+0], v1 = plog[qg*2+1];
        cost += -logf(1.0f/(1.0f + expf(v1-v0)) + EPSV);
        float c0 = clog[qg*2+0], c1 = clog[qg*2+1];
        float pc = isc ? (1.0f/(1.0f + expf(c0-c1))) : (1.0f/(1.0f + expf(c1-c0)));
        cost += -logf(pc + EPSV);

        float C = geom + cost;
        out[qg*T_TOT + t]               = C;
        out[Q_TOT*T_TOT + qg*T_TOT + t] = (float)ido;
    }
}

extern "C" void kernel_launch(void* const* d_in, const int* in_sizes, int n_in,
                              void* d_out, int out_size, void* d_ws, size_t ws_size,
                              hipStream_t stream)
{
    const float* preds  = (const float*)d_in[0];  // pred_curve_points (1,1024,100,3)
    const float* plog   = (const float*)d_in[1];  // pred_curve_logits (1,1024,2)
    const float* ptyp   = (const float*)d_in[2];  // pred_curve_type   (1,1024,4)
    const float* clog   = (const float*)d_in[3];  // closed_curve_logits (1,1024,2)
    const float* tgt    = (const float*)d_in[4];  // tgt_curve_points  (256,100,3)
    const int*   labels = (const int*)d_in[5];    // tgt_labels (256)
    const int*   iscl   = (const int*)d_in[6];    // tgt_is_closed (256)
    const float* clw    = (const float*)d_in[7];  // curve_length_weighting (256)
    float* out = (float*)d_out;

    matcher_main<<<dim3(T_TOT, Q_TOT/128), dim3(512), 0, stream>>>(
        preds, plog, ptyp, clog, tgt, labels, iscl, clw, out);
}